// Round 1
// baseline (337.821 us; speedup 1.0000x reference)
//
#include <hip/hip_runtime.h>

#define BB 64
#define TT 2000
#define DENC 512
#define IDIM 512
#define HID 256
#define KK 10

// ---------------------------------------------------------------------------
// Kernel 1: per-batch 2-layer MLP head.
//   h = tanh(W1 @ state + b1)        (256x512 matvec per batch)
//   z_o = W2[o] @ h + b2[o]          (only o = 3k and 3k+1 needed)
//   store  ms[b][2k]   = exp(z_{3k})     (mean_k)
//          ms[b][2k+1] = exp(-z_{3k+1})  (1/scale_k)
// softmax over the singleton N axis makes weights == 1 exactly, so the
// 3k+2 channels are never needed.
// grid: BB blocks x 256 threads
// ---------------------------------------------------------------------------
__global__ void mlp_kernel(const float* __restrict__ state,
                           const float* __restrict__ W1,
                           const float* __restrict__ b1,
                           const float* __restrict__ W2,
                           const float* __restrict__ b2,
                           float* __restrict__ ms /* [BB][2*KK] */) {
    __shared__ __align__(16) float s_state[IDIM];
    __shared__ float s_h[HID];
    const int b = blockIdx.x;
    const int t = threadIdx.x;

    const float* st = state + (size_t)b * IDIM;
    s_state[t]       = st[t];
    s_state[t + 256] = st[t + 256];
    __syncthreads();

    // h[t] = tanh(b1[t] + dot(W1[t,:], state))
    const float* w1r = W1 + (size_t)t * IDIM;
    float sum = 0.f;
#pragma unroll 8
    for (int k = 0; k < IDIM; k += 4) {
        float4 w = *(const float4*)(w1r + k);
        float4 s = *(const float4*)(s_state + k);
        sum += w.x * s.x + w.y * s.y + w.z * s.z + w.w * s.w;
    }
    s_h[t] = tanhf(sum + b1[t]);
    __syncthreads();

    if (t < 2 * KK) {
        const int k = t >> 1;
        const int which = t & 1;           // 0 -> mean, 1 -> scale
        const int o = 3 * k + which;
        const float* w2r = W2 + o * HID;
        float z = 0.f;
#pragma unroll 4
        for (int i = 0; i < HID; i++) z += w2r[i] * s_h[i];
        z += b2[o];
        ms[b * 2 * KK + t] = (which == 0) ? expf(z) : expf(-z);
    }
}

// ---------------------------------------------------------------------------
// Kernel 2: align[b,j] = sum_k sigmoid((j+0.5-m_k)/s_k) - sigmoid((j-0.5-m_k)/s_k)
// (weights == 1 from singleton softmax). Also zero-inits the context region
// of d_out (harness poisons it to 0xAA) ahead of kernel 3's atomics.
// grid: 500 blocks x 256 threads (= BB*TT threads exactly)
// ---------------------------------------------------------------------------
__global__ void align_kernel(const float* __restrict__ ms,
                             float* __restrict__ out /* d_out base */) {
    const int gid = blockIdx.x * blockDim.x + threadIdx.x;
    if (gid < BB * DENC) out[gid] = 0.f;       // zero context region
    if (gid >= BB * TT) return;
    const int b = gid / TT;
    const int j = gid - b * TT;
    const float* m = ms + b * 2 * KK;
    const float fj = (float)j;
    float a = 0.f;
#pragma unroll
    for (int k = 0; k < KK; k++) {
        const float mean = m[2 * k];
        const float is   = m[2 * k + 1];
        const float x1 = (fj + 0.5f - mean) * is;
        const float x2 = (fj - 0.5f - mean) * is;
        const float f1 = 1.f / (1.f + expf(-x1));
        const float f2 = 1.f / (1.f + expf(-x2));
        a += f1 - f2;
    }
    out[BB * DENC + gid] = a;                  // align, flat b*TT + j
}

// ---------------------------------------------------------------------------
// Kernel 3: context[b,d] = sum_j align[b,j] * enc_z[b,j,d]
// Per-row dynamic skip: align is ~0 outside a narrow j window, so rows with
// |align| <= 1e-8 are skipped (error bound 2000 * 1e-8 * max|enc| ~ 1e-4,
// far below threshold; in fp32 those reference terms are exactly 0 anyway).
// Branch is block-uniform (all lanes read the same align value).
// grid: dim3(TT/CHUNK, BB) x 256 threads; each thread owns 2 d's (float2).
// ---------------------------------------------------------------------------
#define CHUNK 20
__global__ void ctx_kernel(const float* __restrict__ enc,
                           const float* __restrict__ align_v, /* d_out + BB*DENC */
                           float* __restrict__ ctx /* d_out */) {
    const int b = blockIdx.y;
    const int j0 = blockIdx.x * CHUNK;
    const int d = threadIdx.x * 2;
    const float* arow = align_v + b * TT;
    const float* ebase = enc + (size_t)b * TT * DENC;

    float2 acc = make_float2(0.f, 0.f);
    bool any = false;
#pragma unroll
    for (int jj = 0; jj < CHUNK; jj++) {
        const int j = j0 + jj;
        const float a = arow[j];               // block-uniform broadcast
        if (fabsf(a) > 1e-8f) {                // uniform branch
            any = true;
            const float2 v = *(const float2*)(ebase + (size_t)j * DENC + d);
            acc.x += a * v.x;
            acc.y += a * v.y;
        }
    }
    if (any) {
        atomicAdd(&ctx[b * DENC + d],     acc.x);
        atomicAdd(&ctx[b * DENC + d + 1], acc.y);
    }
}

extern "C" void kernel_launch(void* const* d_in, const int* in_sizes, int n_in,
                              void* d_out, int out_size, void* d_ws, size_t ws_size,
                              hipStream_t stream) {
    const float* state = (const float*)d_in[0];
    const float* enc_z = (const float*)d_in[1];
    const float* W1    = (const float*)d_in[2];
    const float* b1    = (const float*)d_in[3];
    const float* W2    = (const float*)d_in[4];
    const float* b2    = (const float*)d_in[5];
    float* out = (float*)d_out;
    float* ms  = (float*)d_ws;   // [BB][2*KK] floats = 5120 B

    mlp_kernel<<<BB, 256, 0, stream>>>(state, W1, b1, W2, b2, ms);
    align_kernel<<<(BB * TT) / 256, 256, 0, stream>>>(ms, out);
    ctx_kernel<<<dim3(TT / CHUNK, BB), 256, 0, stream>>>(enc_z, out + BB * DENC, out);
}